// Round 1
// baseline (3569.572 us; speedup 1.0000x reference)
//
#include <hip/hip_runtime.h>
#include <hip/hip_bf16.h>
#include <math.h>

// Problem constants (fixed by reference)
#define N_NODES 200000
#define FDIM    256     // F
#define MDIM    128     // M
#define KMIX    8       // K mixtures
#define ATTD    128     // ATT
#define NGRAPH  1024
#define TSN     64      // nodes per block

// ---------------------------------------------------------------------------
// Kernel 1: fused  x@g -> gaussian-mixture -> H  -> attention score
//   grid: N/64 blocks x 256 threads.
//   LDS: x-tile [256][64] transposed (64KB, loaded once) + g-tile [32][128]
//   per-thread C-tile: 4 nodes x 8 m  (32 fp32 acc), H acc persists over k.
// ---------------------------------------------------------------------------
__global__ __launch_bounds__(256) void fused_forward(
    const float* __restrict__ x, const float* __restrict__ g,
    const float* __restrict__ mu, const float* __restrict__ sigma,
    const float* __restrict__ w1, const float* __restrict__ w2,
    float* __restrict__ Hout, float* __restrict__ scores)
{
    __shared__ float xs[FDIM * TSN];   // 64KB, [f][node] (transposed)
    __shared__ float gs[32 * MDIM];    // 16KB, [f_local][m]
    float* Hs = xs;                    // overlay after main loop: [64][132]

    const int tid   = threadIdx.x;
    const int nBase = blockIdx.x * TSN;

    // ---- stage x tile transposed: xs[f][row] ----
    // row = idx&63 -> lanes write consecutive LDS addresses (2-way, free)
    {
        const float4* xg = (const float4*)x;
        for (int r = 0; r < 16; ++r) {
            int idx  = tid + r * 256;
            int row  = idx & 63;
            int quad = idx >> 6;       // 0..63 (f-quad)
            float4 v = xg[(size_t)(nBase + row) * 64 + quad];
            xs[(quad * 4 + 0) * TSN + row] = v.x;
            xs[(quad * 4 + 1) * TSN + row] = v.y;
            xs[(quad * 4 + 2) * TSN + row] = v.z;
            xs[(quad * 4 + 3) * TSN + row] = v.w;
        }
    }

    const int mg  = tid & 15;          // m-group 0..15
    const int ng  = tid >> 4;          // node-group 0..15
    const int m0  = mg * 8;
    const int nl0 = ng * 4;

    float h[4][8];
    #pragma unroll
    for (int i = 0; i < 4; ++i)
        #pragma unroll
        for (int j = 0; j < 8; ++j) h[i][j] = 0.f;

    for (int k = 0; k < KMIX; ++k) {
        float acc[4][8];
        #pragma unroll
        for (int i = 0; i < 4; ++i)
            #pragma unroll
            for (int j = 0; j < 8; ++j) acc[i][j] = 0.f;

        for (int fc = 0; fc < 8; ++fc) {
            __syncthreads();           // protect gs from previous readers (also covers xs visibility at k=0,fc=0)
            // stage gs: g[fc*32 + f_l][k*128 + 4*quad .. +3]
            {
                const float4* gg = (const float4*)g;
                #pragma unroll
                for (int r = 0; r < 4; ++r) {
                    int idx  = tid + r * 256;
                    int f_l  = idx >> 5;   // 0..31
                    int quad = idx & 31;   // 0..31
                    float4 v = gg[(size_t)(fc * 32 + f_l) * 256 + k * 32 + quad];
                    *(float4*)&gs[f_l * MDIM + quad * 4] = v;
                }
            }
            __syncthreads();

            const float* xb = &xs[(fc * 32) * TSN];
            #pragma unroll
            for (int f = 0; f < 32; ++f) {
                float4 xv = *(const float4*)&xb[f * TSN + nl0];
                float4 ga = *(const float4*)&gs[f * MDIM + m0];
                float4 gb = *(const float4*)&gs[f * MDIM + m0 + 4];
#define FMA_ROW(i, xc) \
                acc[i][0] = fmaf(xc, ga.x, acc[i][0]); \
                acc[i][1] = fmaf(xc, ga.y, acc[i][1]); \
                acc[i][2] = fmaf(xc, ga.z, acc[i][2]); \
                acc[i][3] = fmaf(xc, ga.w, acc[i][3]); \
                acc[i][4] = fmaf(xc, gb.x, acc[i][4]); \
                acc[i][5] = fmaf(xc, gb.y, acc[i][5]); \
                acc[i][6] = fmaf(xc, gb.z, acc[i][6]); \
                acc[i][7] = fmaf(xc, gb.w, acc[i][7]);
                FMA_ROW(0, xv.x)
                FMA_ROW(1, xv.y)
                FMA_ROW(2, xv.z)
                FMA_ROW(3, xv.w)
#undef FMA_ROW
            }
        }

        // gaussian chain for this k:  h += out * exp(-0.5*(out-mu)^2/(eps+sigma^2))
        #pragma unroll
        for (int j = 0; j < 8; ++j) {
            float muv = mu[k * MDIM + m0 + j];
            float sg  = sigma[k * MDIM + m0 + j];
            float iv  = 1.0f / (1e-15f + sg * sg);
            #pragma unroll
            for (int i = 0; i < 4; ++i) {
                float o = acc[i][j];
                float d = o - muv;
                h[i][j] += o * __expf(-0.5f * d * d * iv);
            }
        }
    }

    // ---- write H (global + LDS overlay), then attention scores ----
    __syncthreads();                   // all xs reads done before overlay
    const int HS_LD = MDIM + 4;        // pad 4 floats: keeps 16B align, breaks conflicts
    #pragma unroll
    for (int i = 0; i < 4; ++i) {
        int nl = nl0 + i;
        float4 a4 = make_float4(h[i][0], h[i][1], h[i][2], h[i][3]);
        float4 b4 = make_float4(h[i][4], h[i][5], h[i][6], h[i][7]);
        *(float4*)&Hs[nl * HS_LD + m0]     = a4;
        *(float4*)&Hs[nl * HS_LD + m0 + 4] = b4;
        *(float4*)&Hout[(size_t)(nBase + nl) * MDIM + m0]     = a4;
        *(float4*)&Hout[(size_t)(nBase + nl) * MDIM + m0 + 4] = b4;
    }
    __syncthreads();

    // attention: score[n] = sum_att tanh(dot(H[n], w1[att])) * w2[att]
    // 4 threads per node, 32 atts each.
    {
        const int nl  = tid >> 2;
        const int sub = tid & 3;
        const float4* hr = (const float4*)&Hs[nl * HS_LD];
        float sacc = 0.f;
        for (int a = 0; a < 32; ++a) {
            int att = sub * 32 + a;
            const float4* wr = (const float4*)(w1 + att * MDIM);
            float s0 = 0.f, s1 = 0.f, s2 = 0.f, s3 = 0.f;
            #pragma unroll
            for (int mv = 0; mv < 32; ++mv) {
                float4 hv = hr[mv];
                float4 wv = wr[mv];
                s0 = fmaf(hv.x, wv.x, s0);
                s1 = fmaf(hv.y, wv.y, s1);
                s2 = fmaf(hv.z, wv.z, s2);
                s3 = fmaf(hv.w, wv.w, s3);
            }
            float dot = (s0 + s1) + (s2 + s3);
            // tanh(x) = 1 - 2/(e^{2x}+1): monotone-safe at +/-inf, no NaN
            float e2 = __expf(2.f * dot);
            float av = 1.f - 2.f / (e2 + 1.f);
            sacc = fmaf(av, w2[att], sacc);
        }
        sacc += __shfl_down(sacc, 2, 4);
        sacc += __shfl_down(sacc, 1, 4);
        if (sub == 0) scores[nBase + nl] = sacc;
    }
}

// ---------------------------------------------------------------------------
// Kernel 2: per-graph segment softmax + weighted pooling.
//   one block per graph; batch is sorted -> binary search bounds.
// ---------------------------------------------------------------------------
__global__ __launch_bounds__(256) void segment_pool(
    const float* __restrict__ H, const float* __restrict__ scores,
    const int* __restrict__ batch, float* __restrict__ out)
{
    const int gidx = blockIdx.x;
    const int tid  = threadIdx.x;

    // segment bounds [start, end)
    int lo = 0, hi = N_NODES;
    while (lo < hi) { int mid = (lo + hi) >> 1; if (batch[mid] <  gidx) lo = mid + 1; else hi = mid; }
    const int start = lo;
    hi = N_NODES;
    while (lo < hi) { int mid = (lo + hi) >> 1; if (batch[mid] <= gidx) lo = mid + 1; else hi = mid; }
    const int end = lo;

    __shared__ float red[4];

    // ---- segment max ----
    float mx = -INFINITY;
    for (int i = start + tid; i < end; i += 256) mx = fmaxf(mx, scores[i]);
    #pragma unroll
    for (int o = 32; o > 0; o >>= 1) mx = fmaxf(mx, __shfl_xor(mx, o));
    if ((tid & 63) == 0) red[tid >> 6] = mx;
    __syncthreads();
    mx = fmaxf(fmaxf(red[0], red[1]), fmaxf(red[2], red[3]));
    __syncthreads();

    // ---- sum of exp ----
    float s = 0.f;
    for (int i = start + tid; i < end; i += 256) s += __expf(scores[i] - mx);
    #pragma unroll
    for (int o = 32; o > 0; o >>= 1) s += __shfl_xor(s, o);
    if ((tid & 63) == 0) red[tid >> 6] = s;
    __syncthreads();
    s = red[0] + red[1] + red[2] + red[3];
    const float inv = 1.f / (s + 1e-16f);

    // ---- weighted pool: out[g][m] = inv * sum_i exp(score_i - mx) * H[i][m]
    const int m = tid & 127;
    const int p = tid >> 7;
    float acc = 0.f;
    for (int i = start + p; i < end; i += 2)
        acc = fmaf(__expf(scores[i] - mx), H[(size_t)i * MDIM + m], acc);
    __shared__ float part[2][128];
    part[p][m] = acc;
    __syncthreads();
    if (tid < 128) out[gidx * MDIM + tid] = (part[0][tid] + part[1][tid]) * inv;
}

// ---------------------------------------------------------------------------
extern "C" void kernel_launch(void* const* d_in, const int* in_sizes, int n_in,
                              void* d_out, int out_size, void* d_ws, size_t ws_size,
                              hipStream_t stream)
{
    const float* x     = (const float*)d_in[0];
    const float* g     = (const float*)d_in[1];
    const float* mu    = (const float*)d_in[2];
    const float* sigma = (const float*)d_in[3];
    const float* w1    = (const float*)d_in[4];
    const float* w2    = (const float*)d_in[5];
    const int*   batch = (const int*)d_in[6];
    float* out = (float*)d_out;

    // workspace layout: H [N][128] fp32, then scores [N] fp32  (~103.2 MB)
    float* H      = (float*)d_ws;
    float* scores = H + (size_t)N_NODES * MDIM;

    fused_forward<<<N_NODES / TSN, 256, 0, stream>>>(x, g, mu, sigma, w1, w2, H, scores);
    segment_pool<<<NGRAPH, 256, 0, stream>>>(H, scores, batch, out);
}

// Round 2
// 2398.101 us; speedup vs baseline: 1.4885x; 1.4885x over previous
//
#include <hip/hip_runtime.h>
#include <hip/hip_bf16.h>
#include <hip/hip_fp16.h>
#include <math.h>

// Problem constants (fixed by reference)
#define N_NODES 200000
#define FDIM    256     // F
#define MDIM    128     // M
#define KMIX    8       // K mixtures
#define ATTD    128     // ATT
#define NGRAPH  1024
#define TSN     64      // nodes per block

typedef _Float16 half8 __attribute__((ext_vector_type(8)));
typedef _Float16 half4 __attribute__((ext_vector_type(4)));
typedef float    floatx4 __attribute__((ext_vector_type(4)));

// ---------------------------------------------------------------------------
// Kernel 0: split g (fp32) into fp16 hi/lo packed in MFMA B-fragment lane
// order. frag index = (k*8 + ctg)*8 + fc ; per frag 64 lanes x 8 f16 (16B).
// B-frag layout (16x16x32 f16): col = lane&15, k-dim = (lane>>4)*8 + j.
//   gh/gl[frag*512 + lane*8 + j] = split( g[fc*32 + (lane>>4)*8 + j][k*128 + ctg*16 + (lane&15)] )
// ---------------------------------------------------------------------------
__global__ __launch_bounds__(256) void pack_g(
    const float* __restrict__ g, _Float16* __restrict__ gh, _Float16* __restrict__ gl)
{
    int t    = blockIdx.x * 256 + threadIdx.x;   // 0..32767
    int lane = t & 63;
    int frag = t >> 6;         // 0..511
    int fc   = frag & 7;
    int ctg  = (frag >> 3) & 7;
    int k    = frag >> 6;
    int col  = k * 128 + ctg * 16 + (lane & 15);
    int f0   = fc * 32 + (lane >> 4) * 8;
    half8 vh, vl;
    #pragma unroll
    for (int j = 0; j < 8; ++j) {
        float v = g[(size_t)(f0 + j) * 1024 + col];
        _Float16 h = (_Float16)v;
        vh[j] = h;
        vl[j] = (_Float16)(v - (float)h);
    }
    *(half8*)(gh + (size_t)t * 8) = vh;
    *(half8*)(gl + (size_t)t * 8) = vl;
}

// ---------------------------------------------------------------------------
// Kernel 1: fused  x@g (fp16-split MFMA) -> gaussian -> H -> attention score
//   grid: N/64 blocks x 256 threads (4 waves).
//   wave w owns cols w*32..w*32+31 (2 col-tiles of 16) for all 64 nodes.
//   per wave: acc[4 rt][2 ct] fp32x4 C-frags, H accumulated in same layout.
// ---------------------------------------------------------------------------
__global__ __launch_bounds__(256) void fused_forward(
    const float* __restrict__ x,
    const _Float16* __restrict__ gh, const _Float16* __restrict__ gl,
    const float* __restrict__ mu, const float* __restrict__ sigma,
    const float* __restrict__ w1, const float* __restrict__ w2,
    float* __restrict__ Hout, float* __restrict__ scores)
{
    // xs_h/xs_l: [64 nodes][264 f16] (f-dim padded 256->264: 2-way banks, 16B rows)
    // Hs overlay after main loop: [64][132] fp32
    __shared__ unsigned char smem[64 * 264 * 2 * 2];   // 67584 B
    _Float16* xs_h = (_Float16*)smem;
    _Float16* xs_l = xs_h + 64 * 264;
    float*    Hs   = (float*)smem;

    const int tid   = threadIdx.x;
    const int nBase = blockIdx.x * TSN;

    // ---- stage x tile as fp16 hi/lo ----
    {
        const float4* xg = (const float4*)x;   // row = 64 float4
        #pragma unroll
        for (int r = 0; r < 16; ++r) {
            int idx  = r * 256 + tid;
            int row  = idx >> 6;       // 0..63
            int quad = idx & 63;       // f-quad
            float4 v = xg[(size_t)(nBase + row) * 64 + quad];
            half4 h, l;
            h[0] = (_Float16)v.x; l[0] = (_Float16)(v.x - (float)h[0]);
            h[1] = (_Float16)v.y; l[1] = (_Float16)(v.y - (float)h[1]);
            h[2] = (_Float16)v.z; l[2] = (_Float16)(v.z - (float)h[2]);
            h[3] = (_Float16)v.w; l[3] = (_Float16)(v.w - (float)h[3]);
            *(half4*)&xs_h[row * 264 + quad * 4] = h;
            *(half4*)&xs_l[row * 264 + quad * 4] = l;
        }
    }
    __syncthreads();

    const int wave = tid >> 6;
    const int lane = tid & 63;
    const int c15  = lane & 15;
    const int q    = lane >> 4;

    float h[4][2][4];                  // [row-tile][col-tile][reg]
    #pragma unroll
    for (int rt = 0; rt < 4; ++rt)
        #pragma unroll
        for (int ct = 0; ct < 2; ++ct)
            #pragma unroll
            for (int rg = 0; rg < 4; ++rg) h[rt][ct][rg] = 0.f;

    for (int k = 0; k < KMIX; ++k) {
        floatx4 acc[4][2];
        #pragma unroll
        for (int rt = 0; rt < 4; ++rt)
            #pragma unroll
            for (int ct = 0; ct < 2; ++ct) acc[rt][ct] = (floatx4)0.f;

        for (int fc = 0; fc < 8; ++fc) {
            const int f0 = fc * 32 + q * 8;
            half8 Ah[4], Al[4];
            #pragma unroll
            for (int rt = 0; rt < 4; ++rt) {
                int node = rt * 16 + c15;
                Ah[rt] = *(const half8*)&xs_h[node * 264 + f0];
                Al[rt] = *(const half8*)&xs_l[node * 264 + f0];
            }
            half8 Bh[2], Bl[2];
            #pragma unroll
            for (int ct = 0; ct < 2; ++ct) {
                int ctg = wave * 2 + ct;
                size_t off = ((size_t)((k * 8 + ctg) * 8 + fc) * 64 + lane) * 8;
                Bh[ct] = *(const half8*)(gh + off);
                Bl[ct] = *(const half8*)(gl + off);
            }
            #pragma unroll
            for (int rt = 0; rt < 4; ++rt)
                #pragma unroll
                for (int ct = 0; ct < 2; ++ct) {
                    acc[rt][ct] = __builtin_amdgcn_mfma_f32_16x16x32_f16(Ah[rt], Bh[ct], acc[rt][ct], 0, 0, 0);
                    acc[rt][ct] = __builtin_amdgcn_mfma_f32_16x16x32_f16(Ah[rt], Bl[ct], acc[rt][ct], 0, 0, 0);
                    acc[rt][ct] = __builtin_amdgcn_mfma_f32_16x16x32_f16(Al[rt], Bh[ct], acc[rt][ct], 0, 0, 0);
                }
        }

        // gaussian chain on C-frags: col = lane&15, row = q*4 + reg
        #pragma unroll
        for (int ct = 0; ct < 2; ++ct) {
            int col = k * 128 + wave * 32 + ct * 16 + c15;    // index into mu/sigma [K][M]
            float muv = mu[col];
            float sg  = sigma[col];
            float iv  = 1.0f / (1e-15f + sg * sg);
            #pragma unroll
            for (int rt = 0; rt < 4; ++rt)
                #pragma unroll
                for (int rg = 0; rg < 4; ++rg) {
                    float o = acc[rt][ct][rg];
                    float d = o - muv;
                    h[rt][ct][rg] += o * __expf(-0.5f * d * d * iv);
                }
        }
    }

    // ---- write H (global + LDS overlay) ----
    __syncthreads();                   // all xs reads done before Hs overlay
    const int HS_LD = MDIM + 4;
    #pragma unroll
    for (int rt = 0; rt < 4; ++rt)
        #pragma unroll
        for (int ct = 0; ct < 2; ++ct)
            #pragma unroll
            for (int rg = 0; rg < 4; ++rg) {
                int n = rt * 16 + q * 4 + rg;
                int m = wave * 32 + ct * 16 + c15;
                float v = h[rt][ct][rg];
                Hs[n * HS_LD + m] = v;
                Hout[(size_t)(nBase + n) * MDIM + m] = v;
            }
    __syncthreads();

    // ---- attention: score[n] = sum_att tanh(dot(H[n], w1[att])) * w2[att]
    {
        const int nl  = tid >> 2;
        const int sub = tid & 3;
        const float4* hr = (const float4*)&Hs[nl * HS_LD];
        float sacc = 0.f;
        for (int a = 0; a < 32; ++a) {
            int att = sub * 32 + a;
            const float4* wr = (const float4*)(w1 + att * MDIM);
            float s0 = 0.f, s1 = 0.f, s2 = 0.f, s3 = 0.f;
            #pragma unroll
            for (int mv = 0; mv < 32; ++mv) {
                float4 hv = hr[mv];
                float4 wv = wr[mv];
                s0 = fmaf(hv.x, wv.x, s0);
                s1 = fmaf(hv.y, wv.y, s1);
                s2 = fmaf(hv.z, wv.z, s2);
                s3 = fmaf(hv.w, wv.w, s3);
            }
            float dot = (s0 + s1) + (s2 + s3);
            float e2 = __expf(2.f * dot);          // tanh = 1 - 2/(e^2x + 1)
            float av = 1.f - 2.f / (e2 + 1.f);
            sacc = fmaf(av, w2[att], sacc);
        }
        sacc += __shfl_down(sacc, 2, 4);
        sacc += __shfl_down(sacc, 1, 4);
        if (sub == 0) scores[nBase + nl] = sacc;
    }
}

// ---------------------------------------------------------------------------
// Kernel 2: per-graph segment softmax + weighted pooling.
// ---------------------------------------------------------------------------
__global__ __launch_bounds__(256) void segment_pool(
    const float* __restrict__ H, const float* __restrict__ scores,
    const int* __restrict__ batch, float* __restrict__ out)
{
    const int gidx = blockIdx.x;
    const int tid  = threadIdx.x;

    int lo = 0, hi = N_NODES;
    while (lo < hi) { int mid = (lo + hi) >> 1; if (batch[mid] <  gidx) lo = mid + 1; else hi = mid; }
    const int start = lo;
    hi = N_NODES;
    while (lo < hi) { int mid = (lo + hi) >> 1; if (batch[mid] <= gidx) lo = mid + 1; else hi = mid; }
    const int end = lo;

    __shared__ float red[4];

    float mx = -INFINITY;
    for (int i = start + tid; i < end; i += 256) mx = fmaxf(mx, scores[i]);
    #pragma unroll
    for (int o = 32; o > 0; o >>= 1) mx = fmaxf(mx, __shfl_xor(mx, o));
    if ((tid & 63) == 0) red[tid >> 6] = mx;
    __syncthreads();
    mx = fmaxf(fmaxf(red[0], red[1]), fmaxf(red[2], red[3]));
    __syncthreads();

    float s = 0.f;
    for (int i = start + tid; i < end; i += 256) s += __expf(scores[i] - mx);
    #pragma unroll
    for (int o = 32; o > 0; o >>= 1) s += __shfl_xor(s, o);
    if ((tid & 63) == 0) red[tid >> 6] = s;
    __syncthreads();
    s = red[0] + red[1] + red[2] + red[3];
    const float inv = 1.f / (s + 1e-16f);

    const int m = tid & 127;
    const int p = tid >> 7;
    float acc = 0.f;
    for (int i = start + p; i < end; i += 2)
        acc = fmaf(__expf(scores[i] - mx), H[(size_t)i * MDIM + m], acc);
    __shared__ float part[2][128];
    part[p][m] = acc;
    __syncthreads();
    if (tid < 128) out[gidx * MDIM + tid] = (part[0][tid] + part[1][tid]) * inv;
}

// ---------------------------------------------------------------------------
extern "C" void kernel_launch(void* const* d_in, const int* in_sizes, int n_in,
                              void* d_out, int out_size, void* d_ws, size_t ws_size,
                              hipStream_t stream)
{
    const float* x     = (const float*)d_in[0];
    const float* g     = (const float*)d_in[1];
    const float* mu    = (const float*)d_in[2];
    const float* sigma = (const float*)d_in[3];
    const float* w1    = (const float*)d_in[4];
    const float* w2    = (const float*)d_in[5];
    const int*   batch = (const int*)d_in[6];
    float* out = (float*)d_out;

    // ws layout: H [N][128] f32 | scores [N] f32 | gh [512K] f16 | gl [512K] f16
    float*    H      = (float*)d_ws;
    float*    scores = H + (size_t)N_NODES * MDIM;
    _Float16* ghp    = (_Float16*)(scores + N_NODES);
    _Float16* glp    = ghp + (size_t)FDIM * KMIX * MDIM;

    pack_g<<<128, 256, 0, stream>>>(g, ghp, glp);
    fused_forward<<<N_NODES / TSN, 256, 0, stream>>>(x, ghp, glp, mu, sigma, w1, w2, H, scores);
    segment_pool<<<NGRAPH, 256, 0, stream>>>(H, scores, batch, out);
}

// Round 3
// 680.859 us; speedup vs baseline: 5.2427x; 3.5222x over previous
//
#include <hip/hip_runtime.h>
#include <hip/hip_bf16.h>
#include <hip/hip_fp16.h>
#include <math.h>

// Problem constants (fixed by reference)
#define N_NODES 200000
#define FDIM    256     // F
#define MDIM    128     // M
#define KMIX    8       // K mixtures
#define ATTD    128     // ATT
#define NGRAPH  1024
#define TSN     64      // nodes per block

typedef _Float16 half8 __attribute__((ext_vector_type(8)));
typedef _Float16 half4 __attribute__((ext_vector_type(4)));
typedef float    floatx4 __attribute__((ext_vector_type(4)));

// ---------------------------------------------------------------------------
// Kernel 0a: split g (fp32) into fp16 hi/lo packed in MFMA B-fragment order.
// frag idx = (k*8 + ctg)*8 + fc ; per frag 64 lanes x half8.
// B layout (16x16x32 f16): col = lane&15, kdim = (lane>>4)*8 + j.
// ---------------------------------------------------------------------------
__global__ __launch_bounds__(256) void pack_g(
    const float* __restrict__ g, _Float16* __restrict__ gh, _Float16* __restrict__ gl)
{
    int t    = blockIdx.x * 256 + threadIdx.x;   // 0..32767
    int lane = t & 63;
    int frag = t >> 6;         // 0..511
    int fc   = frag & 7;
    int ctg  = (frag >> 3) & 7;
    int k    = frag >> 6;
    int col  = k * 128 + ctg * 16 + (lane & 15);
    int f0   = fc * 32 + (lane >> 4) * 8;
    half8 vh, vl;
    #pragma unroll
    for (int j = 0; j < 8; ++j) {
        float v = g[(size_t)(f0 + j) * 1024 + col];
        _Float16 h = (_Float16)v;
        vh[j] = h;
        vl[j] = (_Float16)(v - (float)h);
    }
    *(half8*)(gh + (size_t)t * 8) = vh;
    *(half8*)(gl + (size_t)t * 8) = vl;
}

// ---------------------------------------------------------------------------
// Kernel 0b: split w1 (fp32 [ATT][M]) into fp16 hi/lo B-fragment order.
// GEMM view: dots[n][att] = sum_m H[n][m] * w1[att][m]; kdim = m (4 chunks),
// cols = att (8 ctg tiles). frag idx = ctg*4 + mc (32 frags).
// ---------------------------------------------------------------------------
__global__ __launch_bounds__(256) void pack_w1(
    const float* __restrict__ w1, _Float16* __restrict__ w1h, _Float16* __restrict__ w1l)
{
    int t    = blockIdx.x * 256 + threadIdx.x;   // 0..2047
    int lane = t & 63;
    int frag = t >> 6;         // 0..31
    int mc   = frag & 3;
    int ctg  = frag >> 2;
    int att  = ctg * 16 + (lane & 15);
    int m0   = mc * 32 + (lane >> 4) * 8;
    half8 vh, vl;
    #pragma unroll
    for (int j = 0; j < 8; ++j) {
        float v = w1[att * MDIM + m0 + j];
        _Float16 h = (_Float16)v;
        vh[j] = h;
        vl[j] = (_Float16)(v - (float)h);
    }
    *(half8*)(w1h + (size_t)t * 8) = vh;
    *(half8*)(w1l + (size_t)t * 8) = vl;
}

// ---------------------------------------------------------------------------
// Kernel 1: fused x@g (fp16-split MFMA) -> gaussian -> H -> attention (MFMA)
//   grid: N/64 blocks x 512 threads (8 waves).
//   wave w: n-half = w>>2 (32 nodes, rt=2), col-quarter = w&3 (32 cols, ct=2).
//   VGPR target <=128 (4 waves/SIMD); LDS 67.5KB -> 2 blocks/CU = 16 waves/CU.
// ---------------------------------------------------------------------------
__global__ __launch_bounds__(512, 4) void fused_forward(
    const float* __restrict__ x,
    const _Float16* __restrict__ gh, const _Float16* __restrict__ gl,
    const float* __restrict__ mu, const float* __restrict__ sigma,
    const _Float16* __restrict__ w1h, const _Float16* __restrict__ w1l,
    const float* __restrict__ w2,
    float* __restrict__ Hout, float* __restrict__ scores)
{
    // xs_h/xs_l: [64 nodes][264 f16]  (row stride 528B -> 2-way bank alias, free)
    __shared__ unsigned char smem[64 * 264 * 2 * 2];   // 67584 B
    _Float16* xs_h = (_Float16*)smem;
    _Float16* xs_l = xs_h + 64 * 264;
    float*    Hs   = (float*)smem;                     // overlay [64][132] f32
    float*    spart = (float*)(smem + 64 * 264 * 2);   // [64][4] att partials

    const int tid   = threadIdx.x;
    const int nBase = blockIdx.x * TSN;

    // ---- stage x tile as fp16 hi/lo ----
    {
        const float4* xg = (const float4*)x;   // 64 float4 per row
        #pragma unroll
        for (int r = 0; r < 8; ++r) {
            int idx  = r * 512 + tid;
            int row  = idx >> 6;       // 0..63
            int quad = idx & 63;       // f-quad
            float4 v = xg[(size_t)(nBase + row) * 64 + quad];
            half4 h, l;
            h[0] = (_Float16)v.x; l[0] = (_Float16)(v.x - (float)h[0]);
            h[1] = (_Float16)v.y; l[1] = (_Float16)(v.y - (float)h[1]);
            h[2] = (_Float16)v.z; l[2] = (_Float16)(v.z - (float)h[2]);
            h[3] = (_Float16)v.w; l[3] = (_Float16)(v.w - (float)h[3]);
            *(half4*)&xs_h[row * 264 + quad * 4] = h;
            *(half4*)&xs_l[row * 264 + quad * 4] = l;
        }
    }
    __syncthreads();

    const int wave  = tid >> 6;
    const int lane  = tid & 63;
    const int c15   = lane & 15;
    const int q     = lane >> 4;
    const int nhalf = wave >> 2;   // 0..1
    const int colq  = wave & 3;    // 0..3

    float h[2][2][4];              // [rt][ct][reg] persistent H accumulator
    #pragma unroll
    for (int rt = 0; rt < 2; ++rt)
        #pragma unroll
        for (int ct = 0; ct < 2; ++ct)
            #pragma unroll
            for (int rg = 0; rg < 4; ++rg) h[rt][ct][rg] = 0.f;

    #pragma unroll 1
    for (int k = 0; k < KMIX; ++k) {
        floatx4 acc[2][2];
        #pragma unroll
        for (int rt = 0; rt < 2; ++rt)
            #pragma unroll
            for (int ct = 0; ct < 2; ++ct) acc[rt][ct] = (floatx4)0.f;

        #pragma unroll 2
        for (int fc = 0; fc < 8; ++fc) {
            const int f0 = fc * 32 + q * 8;
            half8 Ah[2], Al[2];
            #pragma unroll
            for (int rt = 0; rt < 2; ++rt) {
                int node = nhalf * 32 + rt * 16 + c15;
                Ah[rt] = *(const half8*)&xs_h[node * 264 + f0];
                Al[rt] = *(const half8*)&xs_l[node * 264 + f0];
            }
            half8 Bh[2], Bl[2];
            #pragma unroll
            for (int ct = 0; ct < 2; ++ct) {
                int ctg = colq * 2 + ct;
                size_t off = ((size_t)((k * 8 + ctg) * 8 + fc) * 64 + lane) * 8;
                Bh[ct] = *(const half8*)(gh + off);
                Bl[ct] = *(const half8*)(gl + off);
            }
            #pragma unroll
            for (int rt = 0; rt < 2; ++rt)
                #pragma unroll
                for (int ct = 0; ct < 2; ++ct) {
                    acc[rt][ct] = __builtin_amdgcn_mfma_f32_16x16x32_f16(Ah[rt], Bh[ct], acc[rt][ct], 0, 0, 0);
                    acc[rt][ct] = __builtin_amdgcn_mfma_f32_16x16x32_f16(Ah[rt], Bl[ct], acc[rt][ct], 0, 0, 0);
                    acc[rt][ct] = __builtin_amdgcn_mfma_f32_16x16x32_f16(Al[rt], Bh[ct], acc[rt][ct], 0, 0, 0);
                }
        }

        // gaussian epilogue: C layout col = lane&15, row = q*4 + reg
        #pragma unroll
        for (int ct = 0; ct < 2; ++ct) {
            int col = k * 128 + colq * 32 + ct * 16 + c15;
            float muv = mu[col];
            float sg  = sigma[col];
            float iv  = 1.0f / (1e-15f + sg * sg);
            #pragma unroll
            for (int rt = 0; rt < 2; ++rt)
                #pragma unroll
                for (int rg = 0; rg < 4; ++rg) {
                    float o = acc[rt][ct][rg];
                    float d = o - muv;
                    h[rt][ct][rg] += o * __expf(-0.5f * d * d * iv);
                }
        }
    }

    // ---- write H (global + LDS overlay) ----
    __syncthreads();                   // all xs reads done before Hs overlay
    const int HS_LD = MDIM + 4;
    #pragma unroll
    for (int rt = 0; rt < 2; ++rt)
        #pragma unroll
        for (int ct = 0; ct < 2; ++ct)
            #pragma unroll
            for (int rg = 0; rg < 4; ++rg) {
                int n = nhalf * 32 + rt * 16 + q * 4 + rg;
                int m = colq * 32 + ct * 16 + c15;
                float v = h[rt][ct][rg];
                Hs[n * HS_LD + m] = v;
                Hout[(size_t)(nBase + n) * MDIM + m] = v;
            }
    __syncthreads();

    // ---- attention via MFMA: dots = H @ w1^T (fp16 split), same wave tiling
    {
        floatx4 datt[2][2];
        #pragma unroll
        for (int rt = 0; rt < 2; ++rt)
            #pragma unroll
            for (int ct = 0; ct < 2; ++ct) datt[rt][ct] = (floatx4)0.f;

        #pragma unroll
        for (int mc = 0; mc < 4; ++mc) {
            half8 Ah[2], Al[2];
            #pragma unroll
            for (int rt = 0; rt < 2; ++rt) {
                int node = nhalf * 32 + rt * 16 + c15;
                const float* hp = &Hs[node * HS_LD + mc * 32 + q * 8];
                #pragma unroll
                for (int j = 0; j < 8; ++j) {
                    float v = hp[j];
                    _Float16 hi = (_Float16)v;
                    Ah[rt][j] = hi;
                    Al[rt][j] = (_Float16)(v - (float)hi);
                }
            }
            #pragma unroll
            for (int ct = 0; ct < 2; ++ct) {
                int frag = (colq * 2 + ct) * 4 + mc;
                size_t off = ((size_t)frag * 64 + lane) * 8;
                half8 Bh = *(const half8*)(w1h + off);
                half8 Bl = *(const half8*)(w1l + off);
                #pragma unroll
                for (int rt = 0; rt < 2; ++rt) {
                    datt[rt][ct] = __builtin_amdgcn_mfma_f32_16x16x32_f16(Ah[rt], Bh, datt[rt][ct], 0, 0, 0);
                    datt[rt][ct] = __builtin_amdgcn_mfma_f32_16x16x32_f16(Ah[rt], Bl, datt[rt][ct], 0, 0, 0);
                    datt[rt][ct] = __builtin_amdgcn_mfma_f32_16x16x32_f16(Al[rt], Bh, datt[rt][ct], 0, 0, 0);
                }
            }
        }

        // tanh * w2, reduce over wave's 32 atts -> spart[node][colq]
        float w2v[2];
        #pragma unroll
        for (int ct = 0; ct < 2; ++ct) w2v[ct] = w2[colq * 32 + ct * 16 + c15];

        #pragma unroll
        for (int rt = 0; rt < 2; ++rt) {
            #pragma unroll
            for (int rg = 0; rg < 4; ++rg) {
                float p = 0.f;
                #pragma unroll
                for (int ct = 0; ct < 2; ++ct) {
                    float dot = datt[rt][ct][rg];
                    float e2 = __expf(2.f * dot);      // tanh = 1 - 2/(e^2x+1)
                    float av = 1.f - 2.f / (e2 + 1.f);
                    p = fmaf(av, w2v[ct], p);
                }
                // sum across the 16 lanes of each q-group (att dimension)
                p += __shfl_xor(p, 1);
                p += __shfl_xor(p, 2);
                p += __shfl_xor(p, 4);
                p += __shfl_xor(p, 8);
                if (c15 == 0) {
                    int n = nhalf * 32 + rt * 16 + q * 4 + rg;
                    spart[n * 4 + colq] = p;
                }
            }
        }
    }
    __syncthreads();
    if (tid < 64) {
        const float* sp = &spart[tid * 4];
        scores[nBase + tid] = (sp[0] + sp[1]) + (sp[2] + sp[3]);
    }
}

// ---------------------------------------------------------------------------
// Kernel 2: per-graph segment softmax + weighted pooling.
// ---------------------------------------------------------------------------
__global__ __launch_bounds__(256) void segment_pool(
    const float* __restrict__ H, const float* __restrict__ scores,
    const int* __restrict__ batch, float* __restrict__ out)
{
    const int gidx = blockIdx.x;
    const int tid  = threadIdx.x;

    int lo = 0, hi = N_NODES;
    while (lo < hi) { int mid = (lo + hi) >> 1; if (batch[mid] <  gidx) lo = mid + 1; else hi = mid; }
    const int start = lo;
    hi = N_NODES;
    while (lo < hi) { int mid = (lo + hi) >> 1; if (batch[mid] <= gidx) lo = mid + 1; else hi = mid; }
    const int end = lo;

    __shared__ float red[4];

    float mx = -INFINITY;
    for (int i = start + tid; i < end; i += 256) mx = fmaxf(mx, scores[i]);
    #pragma unroll
    for (int o = 32; o > 0; o >>= 1) mx = fmaxf(mx, __shfl_xor(mx, o));
    if ((tid & 63) == 0) red[tid >> 6] = mx;
    __syncthreads();
    mx = fmaxf(fmaxf(red[0], red[1]), fmaxf(red[2], red[3]));
    __syncthreads();

    float s = 0.f;
    for (int i = start + tid; i < end; i += 256) s += __expf(scores[i] - mx);
    #pragma unroll
    for (int o = 32; o > 0; o >>= 1) s += __shfl_xor(s, o);
    if ((tid & 63) == 0) red[tid >> 6] = s;
    __syncthreads();
    s = red[0] + red[1] + red[2] + red[3];
    const float inv = 1.f / (s + 1e-16f);

    const int m = tid & 127;
    const int p = tid >> 7;
    float acc = 0.f;
    for (int i = start + p; i < end; i += 2)
        acc = fmaf(__expf(scores[i] - mx), H[(size_t)i * MDIM + m], acc);
    __shared__ float part[2][128];
    part[p][m] = acc;
    __syncthreads();
    if (tid < 128) out[gidx * MDIM + tid] = (part[0][tid] + part[1][tid]) * inv;
}

// ---------------------------------------------------------------------------
extern "C" void kernel_launch(void* const* d_in, const int* in_sizes, int n_in,
                              void* d_out, int out_size, void* d_ws, size_t ws_size,
                              hipStream_t stream)
{
    const float* x     = (const float*)d_in[0];
    const float* g     = (const float*)d_in[1];
    const float* mu    = (const float*)d_in[2];
    const float* sigma = (const float*)d_in[3];
    const float* w1    = (const float*)d_in[4];
    const float* w2    = (const float*)d_in[5];
    const int*   batch = (const int*)d_in[6];
    float* out = (float*)d_out;

    // ws: H [N][128] f32 | scores [N] f32 | gh | gl | w1h | w1l
    float*    H      = (float*)d_ws;
    float*    scores = H + (size_t)N_NODES * MDIM;
    _Float16* ghp    = (_Float16*)(scores + N_NODES);
    _Float16* glp    = ghp + (size_t)FDIM * KMIX * MDIM;
    _Float16* w1hp   = glp + (size_t)FDIM * KMIX * MDIM;
    _Float16* w1lp   = w1hp + (size_t)ATTD * MDIM;

    pack_g<<<128, 256, 0, stream>>>(g, ghp, glp);
    pack_w1<<<8, 256, 0, stream>>>(w1, w1hp, w1lp);
    fused_forward<<<N_NODES / TSN, 512, 0, stream>>>(x, ghp, glp, mu, sigma,
                                                     w1hp, w1lp, w2, H, scores);
    segment_pool<<<NGRAPH, 256, 0, stream>>>(H, scores, batch, out);
}